// Round 8
// baseline (438.401 us; speedup 1.0000x reference)
//
#include <hip/hip_runtime.h>

// Problem constants
#define IN_F 4096
#define OUT_F 12288
#define BATCH 8
#define NGROUPS 32

// 256 blocks (1/CU), 512 threads = 8 waves, 6 consecutive rows per wave
// (= contiguous 96 KB qweight slab per wave), processed as 3 row-pairs.
// Per step: 4 KB contiguous from each of 2 rows, double-buffered.
#define ROWS_PER_WAVE 6
#define ROWS_PER_BLOCK 48
#define NBLOCKS (OUT_F / ROWS_PER_BLOCK)  // 256
#define THREADS 512

__global__ __launch_bounds__(THREADS, 2)
void w4a32_gemv(const float* __restrict__ x,
                const int* __restrict__ qw,
                const float* __restrict__ scales,
                const float* __restrict__ zeros,
                float* __restrict__ out)
{
    __shared__ float xs[BATCH][IN_F];                  // 128 KB
    __shared__ float szs[NGROUPS * ROWS_PER_BLOCK];    // 6 KB scale
    __shared__ float szc[NGROUPS * ROWS_PER_BLOCK];    // 6 KB cc = z - 8*s

    const int tid   = threadIdx.x;
    const int wave  = tid >> 6;
    const int lane  = tid & 63;
    const int rowb  = blockIdx.x * ROWS_PER_BLOCK;
    const int wrow  = wave * ROWS_PER_WAVE;
    const int klane = lane << 2;

    // Wave's contiguous slab: rows (rowb+wrow) .. +5 == 96 KB sequential.
    const int* __restrict__ qw0 = qw + (size_t)(rowb + wrow) * IN_F + klane;

    // step (p, s): pair p=0..2 (rows 2p,2p+1), s=0..3 (4 KB segment of row)
    // row0: qw0 + 2p*IN_F + s*1024 + q*256, q=0..3 ; row1: +IN_F
#define ISSUE(B, p, s) do {                                                  \
    const int* _r0 = qw0 + (p) * 2 * IN_F + (s) * 1024;                      \
    _Pragma("unroll")                                                        \
    for (int q = 0; q < 4; ++q) {                                            \
        B[q]     = *reinterpret_cast<const int4*>(_r0 + q * 256);            \
        B[4 + q] = *reinterpret_cast<const int4*>(_r0 + IN_F + q * 256);     \
    } } while (0)

    // Issue first step's loads before staging: latency hides under staging.
    int4 S0[8], S1[8];
    ISSUE(S0, 0, 0);

    // Stage all of x: 8192 float4 / 512 threads = 16 each, coalesced.
#pragma unroll
    for (int j = 0; j < 16; ++j) {
        const int idx = tid + j * THREADS;
        const int b   = idx >> 10;
        const int kk  = (idx & 1023) << 2;
        *reinterpret_cast<float4*>(&xs[b][kk]) =
            *reinterpret_cast<const float4*>(&x[b * IN_F + kk]);
    }
    // Stage scale and cc = z - 8*s for this block's 48 rows.
#pragma unroll
    for (int j = 0; j < 4; ++j) {
        const int idx = tid + j * THREADS;             // 0..2047
        const int g   = idx >> 6;
        const int r   = idx & 63;
        if (r < ROWS_PER_BLOCK) {
            const float s = scales[g * OUT_F + rowb + r];
            const float z = zeros [g * OUT_F + rowb + r];
            szs[g * ROWS_PER_BLOCK + r] = s;
            szc[g * ROWS_PER_BLOCK + r] = __builtin_fmaf(s, -8.f, z);
        }
    }
    __syncthreads();  // the ONLY barrier

    float acc0[BATCH], acc1[BATCH];

    // Consume one step: 4 chunks (c = 4s..4s+3) for rows (2p, 2p+1).
    // xr loaded once per chunk, used by both rows (LDS amortization).
#define CONSUME(B, p, s) do {                                                \
    _Pragma("unroll")                                                        \
    for (int q = 0; q < 4; ++q) {                                            \
        const int c = (s) * 4 + q;                                           \
        const int g = 2 * c + (lane >> 5);                                   \
        float4 xr[BATCH];                                                    \
        _Pragma("unroll")                                                    \
        for (int b = 0; b < BATCH; ++b)                                      \
            xr[b] = *reinterpret_cast<const float4*>(&xs[b][c * 256 + klane]);\
        const int lr = wrow + 2 * (p);                                       \
        const float s0  = szs[g * ROWS_PER_BLOCK + lr];                      \
        const float cc0 = szc[g * ROWS_PER_BLOCK + lr];                      \
        const float s1  = szs[g * ROWS_PER_BLOCK + lr + 1];                  \
        const float cc1 = szc[g * ROWS_PER_BLOCK + lr + 1];                  \
        const int4 qa = B[q];                                                \
        const int4 qb = B[4 + q];                                            \
        const float a0 = __builtin_fmaf((float)qa.x, s0, cc0);               \
        const float a1 = __builtin_fmaf((float)qa.y, s0, cc0);               \
        const float a2 = __builtin_fmaf((float)qa.z, s0, cc0);               \
        const float a3 = __builtin_fmaf((float)qa.w, s0, cc0);               \
        const float b0 = __builtin_fmaf((float)qb.x, s1, cc1);               \
        const float b1 = __builtin_fmaf((float)qb.y, s1, cc1);               \
        const float b2 = __builtin_fmaf((float)qb.z, s1, cc1);               \
        const float b3 = __builtin_fmaf((float)qb.w, s1, cc1);               \
        _Pragma("unroll")                                                    \
        for (int b = 0; b < BATCH; ++b) {                                    \
            float u = acc0[b], v = acc1[b];                                  \
            u = __builtin_fmaf(a0, xr[b].x, u);                              \
            v = __builtin_fmaf(b0, xr[b].x, v);                              \
            u = __builtin_fmaf(a1, xr[b].y, u);                              \
            v = __builtin_fmaf(b1, xr[b].y, v);                              \
            u = __builtin_fmaf(a2, xr[b].z, u);                              \
            v = __builtin_fmaf(b2, xr[b].z, v);                              \
            u = __builtin_fmaf(a3, xr[b].w, u);                              \
            v = __builtin_fmaf(b3, xr[b].w, v);                              \
            acc0[b] = u; acc1[b] = v;                                        \
        }                                                                    \
    } } while (0)

    for (int p = 0; p < 3; ++p) {
#pragma unroll
        for (int b = 0; b < BATCH; ++b) { acc0[b] = 0.f; acc1[b] = 0.f; }

        ISSUE(S1, p, 1);
        CONSUME(S0, p, 0);
        ISSUE(S0, p, 2);
        CONSUME(S1, p, 1);
        ISSUE(S1, p, 3);
        CONSUME(S0, p, 2);
        if (p < 2) ISSUE(S0, p + 1, 0);   // cross-pair prefetch (uniform branch)
        CONSUME(S1, p, 3);

        // Reduce + store rows (2p, 2p+1)
#pragma unroll
        for (int rr = 0; rr < 2; ++rr) {
            const int n = rowb + wrow + 2 * p + rr;
#pragma unroll
            for (int b = 0; b < BATCH; ++b) {
                float v = rr ? acc1[b] : acc0[b];
                v += __shfl_xor(v, 32);
                v += __shfl_xor(v, 16);
                v += __shfl_xor(v, 8);
                v += __shfl_xor(v, 4);
                v += __shfl_xor(v, 2);
                v += __shfl_xor(v, 1);
                if (lane == b) out[b * OUT_F + n] = v;
            }
        }
    }
#undef ISSUE
#undef CONSUME
}

extern "C" void kernel_launch(void* const* d_in, const int* in_sizes, int n_in,
                              void* d_out, int out_size, void* d_ws, size_t ws_size,
                              hipStream_t stream) {
    const float* x      = (const float*)d_in[0];
    const int*   qw     = (const int*)d_in[1];
    const float* scales = (const float*)d_in[2];
    const float* zeros  = (const float*)d_in[3];
    float* out = (float*)d_out;

    w4a32_gemv<<<NBLOCKS, THREADS, 0, stream>>>(x, qw, scales, zeros, out);
}

// Round 9
// 43.298 us; speedup vs baseline: 10.1252x; 10.1252x over previous
//
#include <hip/hip_runtime.h>

// Problem constants
#define IN_F 4096
#define OUT_F 12288
#define BATCH 8
#define NGROUPS 32

// 256 blocks (1/CU), 1024 threads = 16 waves (4 per SIMD for TLP),
// 3 consecutive rows per wave, 48 rows/block.
// x (128 KB) + scale/cc tables (12 KB) staged to LDS once; single barrier.
// qweight loads are non-temporal (pure stream, no reuse).
#define ROWS_PER_WAVE 3
#define ROWS_PER_BLOCK 48
#define NBLOCKS (OUT_F / ROWS_PER_BLOCK)  // 256
#define THREADS 1024
#define CHUNK 256
#define NCHUNKS (IN_F / CHUNK)            // 16

typedef int v4i __attribute__((ext_vector_type(4)));

__global__ __launch_bounds__(THREADS, 4)   // 4 waves/SIMD -> VGPR cap 128, no spills
void w4a32_gemv(const float* __restrict__ x,
                const int* __restrict__ qw,
                const float* __restrict__ scales,
                const float* __restrict__ zeros,
                float* __restrict__ out)
{
    __shared__ float xs[BATCH][IN_F];                  // 128 KB
    __shared__ float szs[NGROUPS * ROWS_PER_BLOCK];    // 6 KB scale
    __shared__ float szc[NGROUPS * ROWS_PER_BLOCK];    // 6 KB cc = z - 8*s

    const int tid   = threadIdx.x;
    const int wave  = tid >> 6;
    const int lane  = tid & 63;
    const int rowb  = blockIdx.x * ROWS_PER_BLOCK;
    const int wrow  = wave * ROWS_PER_WAVE;            // 0,3,...,45
    const int klane = lane << 2;

    const int* __restrict__ qbase = qw + (size_t)(rowb + wrow) * IN_F + klane;

    // Load one 256-k chunk for this wave's 3 rows (1 KB contiguous per row).
#define ISSUE(B, c) do {                                                     \
    _Pragma("unroll")                                                        \
    for (int r = 0; r < ROWS_PER_WAVE; ++r)                                  \
        B[r] = __builtin_nontemporal_load(                                   \
            reinterpret_cast<const v4i*>(qbase + r * IN_F + (c) * CHUNK));   \
    } while (0)

    v4i qA[ROWS_PER_WAVE], qB[ROWS_PER_WAVE];
    ISSUE(qA, 0);   // in flight while we stage x

    // Stage all of x: 8192 float4 / 1024 threads = 8 each, coalesced.
#pragma unroll
    for (int j = 0; j < 8; ++j) {
        const int idx = tid + j * THREADS;             // 0..8191
        const int b   = idx >> 10;                     // 1024 float4 per batch row
        const int kk  = (idx & 1023) << 2;
        *reinterpret_cast<float4*>(&xs[b][kk]) =
            *reinterpret_cast<const float4*>(&x[b * IN_F + kk]);
    }
    // Stage scale and cc = z - 8*s for this block's 48 rows (32 groups).
#pragma unroll
    for (int j = 0; j < 2; ++j) {
        const int idx = tid + j * THREADS;             // 0..2047
        const int g   = idx >> 6;
        const int r   = idx & 63;
        if (r < ROWS_PER_BLOCK) {
            const float s = scales[g * OUT_F + rowb + r];
            const float z = zeros [g * OUT_F + rowb + r];
            szs[g * ROWS_PER_BLOCK + r] = s;
            szc[g * ROWS_PER_BLOCK + r] = __builtin_fmaf(s, -8.f, z);
        }
    }
    __syncthreads();  // the ONLY barrier

    float acc[ROWS_PER_WAVE][BATCH];
#pragma unroll
    for (int r = 0; r < ROWS_PER_WAVE; ++r)
#pragma unroll
        for (int b = 0; b < BATCH; ++b) acc[r][b] = 0.f;

#define CONSUME(B, c) do {                                                   \
    const int g = 2 * (c) + (lane >> 5);                                     \
    float4 xr[BATCH];                                                        \
    _Pragma("unroll")                                                        \
    for (int b = 0; b < BATCH; ++b)                                          \
        xr[b] = *reinterpret_cast<const float4*>(&xs[b][(c) * CHUNK + klane]);\
    _Pragma("unroll")                                                        \
    for (int r = 0; r < ROWS_PER_WAVE; ++r) {                                \
        const float s  = szs[g * ROWS_PER_BLOCK + wrow + r];                 \
        const float cc = szc[g * ROWS_PER_BLOCK + wrow + r];                 \
        const float w0 = __builtin_fmaf((float)B[r][0], s, cc);              \
        const float w1 = __builtin_fmaf((float)B[r][1], s, cc);              \
        const float w2 = __builtin_fmaf((float)B[r][2], s, cc);              \
        const float w3 = __builtin_fmaf((float)B[r][3], s, cc);              \
        _Pragma("unroll")                                                    \
        for (int b = 0; b < BATCH; ++b) {                                    \
            float a = acc[r][b];                                             \
            a = __builtin_fmaf(w0, xr[b].x, a);                              \
            a = __builtin_fmaf(w1, xr[b].y, a);                              \
            a = __builtin_fmaf(w2, xr[b].z, a);                              \
            a = __builtin_fmaf(w3, xr[b].w, a);                              \
            acc[r][b] = a;                                                   \
        }                                                                    \
    } } while (0)

    // 2-deep pipeline over 16 chunks; named buffers only.
    for (int c = 0; c < NCHUNKS; c += 2) {
        ISSUE(qB, c + 1);
        CONSUME(qA, c);
        if (c + 2 < NCHUNKS) ISSUE(qA, c + 2);
        CONSUME(qB, c + 1);
    }
#undef ISSUE
#undef CONSUME

    // Cross-lane reduction + store (lanes 0..7 hold the 8 batches)
#pragma unroll
    for (int r = 0; r < ROWS_PER_WAVE; ++r) {
        const int n = rowb + wrow + r;
#pragma unroll
        for (int b = 0; b < BATCH; ++b) {
            float v = acc[r][b];
            v += __shfl_xor(v, 32);
            v += __shfl_xor(v, 16);
            v += __shfl_xor(v, 8);
            v += __shfl_xor(v, 4);
            v += __shfl_xor(v, 2);
            v += __shfl_xor(v, 1);
            if (lane == b) out[b * OUT_F + n] = v;
        }
    }
}

extern "C" void kernel_launch(void* const* d_in, const int* in_sizes, int n_in,
                              void* d_out, int out_size, void* d_ws, size_t ws_size,
                              hipStream_t stream) {
    const float* x      = (const float*)d_in[0];
    const int*   qw     = (const int*)d_in[1];
    const float* scales = (const float*)d_in[2];
    const float* zeros  = (const float*)d_in[3];
    float* out = (float*)d_out;

    w4a32_gemv<<<NBLOCKS, THREADS, 0, stream>>>(x, qw, scales, zeros, out);
}